// Round 11
// baseline (26.972 us; speedup 1.0000x reference)
//
#include <hip/hip_runtime.h>

#define DEV __device__ __forceinline__

typedef _Float16 h2 __attribute__((ext_vector_type(2)));
typedef float    f2 __attribute__((ext_vector_type(2)));

DEV float fast_rcp(float x) { return __builtin_amdgcn_rcpf(x); }

DEV float fexp2(float x) {
#if __has_builtin(__builtin_amdgcn_exp2f)
    return __builtin_amdgcn_exp2f(x);
#else
    float r; asm("v_exp_f32 %0, %1" : "=v"(r) : "v"(x)); return r;
#endif
}

DEV float dot2acc(h2 a, h2 b, float c) {
#if __has_builtin(__builtin_amdgcn_fdot2)
    return __builtin_amdgcn_fdot2(a, b, c, false);
#else
    return c + (float)a.x * (float)b.x + (float)a.y * (float)b.y;
#endif
}

// acc = w2 * in2 + acc (packed f32). w2 uniform -> SGPR pair.
DEV void pk_fma(f2& acc, f2 w2, f2 in2) {
    asm("v_pk_fma_f32 %0, %1, %2, %0" : "+v"(acc) : "s"(w2), "v"(in2));
}
// acc = w2 * in2 + 0  (inline-0 C: no accumulator init movs).
DEV f2 pk_fma_z(f2 w2, f2 in2) {
    f2 d;
    asm("v_pk_fma_f32 %0, %1, %2, 0 op_sel_hi:[1,1,0]"
        : "=v"(d) : "s"(w2), "v"(in2));
    return d;
}
// acc += broadcast(e.x) * du   (du = {1.0, u} pair straight from LDS).
DEV void pk_fma_bcast(f2& acc, f2 e, f2 du) {
    asm("v_pk_fma_f32 %0, %1, %2, %0 op_sel:[0,0,0] op_sel_hi:[0,1,1]"
        : "+v"(acc) : "v"(e), "v"(du));
}

// tanh from pre-scaled input t = 2*log2(e)*(Wx+b): 1 - 2/(exp2(t)+1).
DEV float fast_tanh_pre(float t) {
    float e = fexp2(t);
    return 1.0f - 2.0f * fast_rcp(e + 1.0f);
}
DEV float fast_sigmoid(float x) {
    return fast_rcp(1.0f + fexp2(x * -1.442695041f));
}

#define TANH_K 2.885390082f   // 2*log2(e)

// MLP layer on f2-native activations; input-pair packed weights via uniform
// s_load_dwordx2; bias folded into the tanh-input FMA.
template <int IN, int OUT, bool TANH>
DEV void layer_pk(const float* __restrict__ w, const float* __restrict__ b,
                  float vK, const f2 (&in)[IN / 2], f2 (&out)[OUT / 2]) {
    #pragma unroll
    for (int o = 0; o < OUT; ++o) {
        f2 acc = pk_fma_z(*reinterpret_cast<const f2*>(w + o * IN), in[0]);
        #pragma unroll
        for (int ip = 1; ip < IN / 2; ++ip)
            pk_fma(acc, *reinterpret_cast<const f2*>(w + o * IN + 2 * ip), in[ip]);
        float s = acc.x + acc.y;
        float r;
        if (TANH) {
            float bk = b[o] * vK;
            r = fast_tanh_pre(fmaf(s, vK, bk));
        } else {
            r = s;
        }
        if (o & 1) out[o >> 1].y = r; else out[o >> 1].x = r;
    }
}

__global__ __launch_bounds__(512, 8)   // force VGPR<=64 -> 8 waves/SIMD
void qcnn_fused_kernel(const float* __restrict__ x,
                       const float* __restrict__ w_fm, const float* __restrict__ b_fm,
                       const float* __restrict__ w_c1, const float* __restrict__ b_c1,
                       const float* __restrict__ w_p1, const float* __restrict__ b_p1,
                       const float* __restrict__ w_c2, const float* __restrict__ b_c2,
                       const float* __restrict__ w_p2, const float* __restrict__ b_p2,
                       const float* __restrict__ w_c3, const float* __restrict__ b_c3,
                       const float* __restrict__ w_q,  const float* __restrict__ w_k,
                       const float* __restrict__ w_v,
                       const float* __restrict__ w_fc, const float* __restrict__ b_fc,
                       float* __restrict__ out) {
    const int t     = threadIdx.x;          // 0..511
    const int sub   = t >> 8;               // sub-batch 0/1
    const int tid   = t & 255;
    const int tok   = tid & 127;            // token
    const int jh    = tid >> 7;             // j-half 0/1, wave-uniform
    const int batch = blockIdx.x * 2 + sub; // 0..2047

    // per-token entry: x=k01(fp16x2) y=k23(fp16x2) z=1.0f w=u(f32)
    __shared__ uint4 kvbuf[2][128];
    __shared__ f2    pp[2][128];            // jh=1 partial {denom, numer}

    const float vK = TANH_K;

    // ---- load x (both jh threads load the same row; L1 absorbs) ----
    const float* xp = x + ((size_t)batch * 128 + tok) * 8;
    float4 x0 = *reinterpret_cast<const float4*>(xp);
    float4 x1 = *reinterpret_cast<const float4*>(xp + 4);
    f2 xin[4] = {f2{x0.x, x0.y}, f2{x0.z, x0.w}, f2{x1.x, x1.y}, f2{x1.z, x1.w}};

    // ---- MLP tower (duplicated across the jh pair; no exchanges) ----
    f2 h1[8], h2a[8], h3[6], h4[4], h5[2], h6[2];
    layer_pk<8, 16, true>(w_fm, b_fm, vK, xin, h1);
    layer_pk<16, 16, true>(w_c1, b_c1, vK, h1, h2a);
    layer_pk<16, 12, true>(w_p1, b_p1, vK, h2a, h3);
    layer_pk<12, 8, true>(w_c2, b_c2, vK, h3, h4);
    layer_pk<8, 4, true>(w_p2, b_p2, vK, h4, h5);
    layer_pk<4, 4, true>(w_c3, b_c3, vK, h5, h6);

    f2 qv2[2];
    layer_pk<4, 4, false>(w_q, nullptr, vK, h6, qv2);
    const float QS = 0.7213475204f;   // log2(e)/sqrt(4)
    h2 q01 = {(_Float16)(qv2[0].x * QS), (_Float16)(qv2[0].y * QS)};
    h2 q23 = {(_Float16)(qv2[1].x * QS), (_Float16)(qv2[1].y * QS)};

    if (jh == 0) {    // wave-uniform: only jh=0 waves produce K and u
        f2 kk2[2];
        layer_pk<4, 4, false>(w_k, nullptr, vK, h6, kk2);
        float wf[4];
        #pragma unroll
        for (int i = 0; i < 4; ++i)
            wf[i] = fmaf(w_fc[0], w_v[0 * 4 + i],
                    fmaf(w_fc[1], w_v[1 * 4 + i],
                    fmaf(w_fc[2], w_v[2 * 4 + i], w_fc[3] * w_v[3 * 4 + i])));
        float u = fmaf(wf[0], h6[0].x, fmaf(wf[1], h6[0].y,
                  fmaf(wf[2], h6[1].x, wf[3] * h6[1].y)));
        h2 pk01 = {(_Float16)kk2[0].x, (_Float16)kk2[0].y};
        h2 pk23 = {(_Float16)kk2[1].x, (_Float16)kk2[1].y};
        uint4 ent;
        ent.x = __builtin_bit_cast(unsigned, pk01);
        ent.y = __builtin_bit_cast(unsigned, pk23);
        ent.z = __builtin_bit_cast(unsigned, 1.0f);
        ent.w = __builtin_bit_cast(unsigned, u);
        kvbuf[sub][tok] = ent;
    }
    __syncthreads();

    // ---- attention: this thread's own row over its j-half (64 iters).
    //      kvbuf[sub][j] wave-uniform -> free LDS broadcast. ----
    const uint4* __restrict__ base = kvbuf[sub] + jh * 64;
    f2 acc = {0.f, 0.f};    // {denom, numerator}
    #pragma unroll 8
    for (int j = 0; j < 64; ++j) {
        uint4 c = base[j];
        h2 k01 = __builtin_bit_cast(h2, c.x);
        h2 k23 = __builtin_bit_cast(h2, c.y);
        f2 du;
        du.x = __builtin_bit_cast(float, c.z);   // 1.0f
        du.y = __builtin_bit_cast(float, c.w);   // u
        float s = dot2acc(q01, k01, dot2acc(q23, k23, 0.f));
        f2 e; e.x = fexp2(s);                     // hi word undef (ok)
        pk_fma_bcast(acc, e, du);                 // {d,n} += e * {1,u}
    }

    if (jh == 1) pp[sub][tok] = acc;
    __syncthreads();

    if (jh == 0) {
        f2 o = pp[sub][tok];
        acc += o;
        float z = fmaf(acc.y, fast_rcp(acc.x), b_fc[0]);
        out[(size_t)batch * 128 + tok] = fast_sigmoid(z);
    }
}

extern "C" void kernel_launch(void* const* d_in, const int* in_sizes, int n_in,
                              void* d_out, int out_size, void* d_ws, size_t ws_size,
                              hipStream_t stream) {
    const float* x    = (const float*)d_in[0];
    const float* w_fm = (const float*)d_in[1];
    const float* b_fm = (const float*)d_in[2];
    const float* w_c1 = (const float*)d_in[3];
    const float* b_c1 = (const float*)d_in[4];
    const float* w_p1 = (const float*)d_in[5];
    const float* b_p1 = (const float*)d_in[6];
    const float* w_c2 = (const float*)d_in[7];
    const float* b_c2 = (const float*)d_in[8];
    const float* w_p2 = (const float*)d_in[9];
    const float* b_p2 = (const float*)d_in[10];
    const float* w_c3 = (const float*)d_in[11];
    const float* b_c3 = (const float*)d_in[12];
    const float* w_q  = (const float*)d_in[13];
    const float* w_k  = (const float*)d_in[14];
    const float* w_v  = (const float*)d_in[15];
    const float* w_fc = (const float*)d_in[16];
    const float* b_fc = (const float*)d_in[17];
    float* out = (float*)d_out;

    dim3 grid(1024);   // optimal wg count; 2 batches per block
    dim3 block(512);   // 2 threads/token (j-split), 8 waves/SIMD target
    qcnn_fused_kernel<<<grid, block, 0, stream>>>(
        x, w_fm, b_fm, w_c1, b_c1, w_p1, b_p1, w_c2, b_c2,
        w_p2, b_p2, w_c3, b_c3, w_q, w_k, w_v, w_fc, b_fc, out);
}

// Round 12
// 20.339 us; speedup vs baseline: 1.3261x; 1.3261x over previous
//
#include <hip/hip_runtime.h>

#define DEV __device__ __forceinline__

typedef _Float16 h2 __attribute__((ext_vector_type(2)));
typedef float    f2 __attribute__((ext_vector_type(2)));

DEV float fast_rcp(float x) { return __builtin_amdgcn_rcpf(x); }

DEV float fexp2(float x) {
#if __has_builtin(__builtin_amdgcn_exp2f)
    return __builtin_amdgcn_exp2f(x);
#else
    float r; asm("v_exp_f32 %0, %1" : "=v"(r) : "v"(x)); return r;
#endif
}

DEV float dot2acc(h2 a, h2 b, float c) {
#if __has_builtin(__builtin_amdgcn_fdot2)
    return __builtin_amdgcn_fdot2(a, b, c, false);
#else
    return c + (float)a.x * (float)b.x + (float)a.y * (float)b.y;
#endif
}

// acc = w2 * in2 + acc (packed f32). w2 uniform -> SGPR pair.
DEV void pk_fma(f2& acc, f2 w2, f2 in2) {
    asm("v_pk_fma_f32 %0, %1, %2, %0" : "+v"(acc) : "s"(w2), "v"(in2));
}
// acc = w2 * in2 + 0  (inline-0 C: no accumulator init movs).
DEV f2 pk_fma_z(f2 w2, f2 in2) {
    f2 d;
    asm("v_pk_fma_f32 %0, %1, %2, 0 op_sel_hi:[1,1,0]"
        : "=v"(d) : "s"(w2), "v"(in2));
    return d;
}
// acc += broadcast(e.x) * du   (du = {1.0, u} pair straight from LDS).
DEV void pk_fma_bcast(f2& acc, f2 e, f2 du) {
    asm("v_pk_fma_f32 %0, %1, %2, %0 op_sel:[0,0,0] op_sel_hi:[0,1,1]"
        : "+v"(acc) : "v"(e), "v"(du));
}

// tanh from pre-scaled input t = 2*log2(e)*(Wx+b): 1 - 2/(exp2(t)+1).
DEV float fast_tanh_pre(float t) {
    float e = fexp2(t);
    return 1.0f - 2.0f * fast_rcp(e + 1.0f);
}
DEV float fast_sigmoid(float x) {
    return fast_rcp(1.0f + fexp2(x * -1.442695041f));
}

#define TANH_K 2.885390082f   // 2*log2(e)

// MLP layer, input-pair packed weights via uniform s_load_dwordx2.
// Bias folded into the tanh-input FMA: t = dot*K + (b*K).
template <int IN, int OUT, bool TANH>
DEV void layer_pk(const float* __restrict__ w, const float* __restrict__ b,
                  float vK, const float (&in)[IN], float (&out)[OUT]) {
    static_assert(IN % 2 == 0, "IN must be even");
    f2 in2[IN / 2];
    #pragma unroll
    for (int ip = 0; ip < IN / 2; ++ip) in2[ip] = f2{in[2 * ip], in[2 * ip + 1]};
    #pragma unroll
    for (int o = 0; o < OUT; ++o) {
        f2 acc = pk_fma_z(*reinterpret_cast<const f2*>(w + o * IN), in2[0]);
        #pragma unroll
        for (int ip = 1; ip < IN / 2; ++ip)
            pk_fma(acc, *reinterpret_cast<const f2*>(w + o * IN + 2 * ip), in2[ip]);
        float s = acc.x + acc.y;
        if (TANH) {
            float bk = b[o] * vK;           // v_mul: sgpr bias x vgpr K
            out[o] = fast_tanh_pre(fmaf(s, vK, bk));
        } else {
            out[o] = s;
        }
    }
}

DEV f2 shfl_f2(f2 v, int m) {
    f2 r;
    r.x = __shfl_xor(v.x, m);
    r.y = __shfl_xor(v.y, m);
    return r;
}

__global__ __launch_bounds__(256)
void qcnn_fused_kernel(const float* __restrict__ x,
                       const float* __restrict__ w_fm, const float* __restrict__ b_fm,
                       const float* __restrict__ w_c1, const float* __restrict__ b_c1,
                       const float* __restrict__ w_p1, const float* __restrict__ b_p1,
                       const float* __restrict__ w_c2, const float* __restrict__ b_c2,
                       const float* __restrict__ w_p2, const float* __restrict__ b_p2,
                       const float* __restrict__ w_c3, const float* __restrict__ b_c3,
                       const float* __restrict__ w_q,  const float* __restrict__ w_k,
                       const float* __restrict__ w_v,
                       const float* __restrict__ w_fc, const float* __restrict__ b_fc,
                       float* __restrict__ out) {
    const int t     = threadIdx.x;          // 0..255
    const int bb    = t >> 7;               // sub-batch 0/1 within block
    const int tok   = t & 127;              // token 0..127
    const int batch = blockIdx.x * 2 + bb;  // 0..2047
    const int qd    = t & 3;                // lane-quad slot

    // per-token entry: x=k01(fp16x2) y=k23(fp16x2) z=1.0f w=u(f32)
    __shared__ uint4 kvbuf[2][128];

    const float vK = TANH_K;                // hoisted VGPR constant

    // ---- load x[batch][tok][0:8] (coalesced, 32 B/thread) ----
    const float* xp = x + ((size_t)batch * 128 + tok) * 8;
    float4 x0 = *reinterpret_cast<const float4*>(xp);
    float4 x1 = *reinterpret_cast<const float4*>(xp + 4);
    float xin[8] = {x0.x, x0.y, x0.z, x0.w, x1.x, x1.y, x1.z, x1.w};

    // ---- MLP tower, packed-pair f32 FMA; weights via uniform scalar loads ----
    float h1[16], h2a[16], h3[12], h4[8], h5[4], h6[4];
    layer_pk<8, 16, true>(w_fm, b_fm, vK, xin, h1);
    layer_pk<16, 16, true>(w_c1, b_c1, vK, h1, h2a);
    layer_pk<16, 12, true>(w_p1, b_p1, vK, h2a, h3);
    layer_pk<12, 8, true>(w_c2, b_c2, vK, h3, h4);
    layer_pk<8, 4, true>(w_p2, b_p2, vK, h4, h5);
    layer_pk<4, 4, true>(w_c3, b_c3, vK, h5, h6);

    float qv[4], kk[4];
    layer_pk<4, 4, false>(w_q, nullptr, vK, h6, qv);
    layer_pk<4, 4, false>(w_k, nullptr, vK, h6, kk);

    // ---- fc folded into V: u = (w_fc^T W_v) . h6 (uniform weights) ----
    float wf[4];
    #pragma unroll
    for (int i = 0; i < 4; ++i)
        wf[i] = fmaf(w_fc[0], w_v[0 * 4 + i],
                fmaf(w_fc[1], w_v[1 * 4 + i],
                fmaf(w_fc[2], w_v[2 * 4 + i], w_fc[3] * w_v[3 * 4 + i])));
    float u = fmaf(wf[0], h6[0], fmaf(wf[1], h6[1], fmaf(wf[2], h6[2], wf[3] * h6[3])));

    h2 pk01 = {(_Float16)kk[0], (_Float16)kk[1]};
    h2 pk23 = {(_Float16)kk[2], (_Float16)kk[3]};
    uint4 ent;
    ent.x = __builtin_bit_cast(unsigned, pk01);
    ent.y = __builtin_bit_cast(unsigned, pk23);
    ent.z = __builtin_bit_cast(unsigned, 1.0f);   // pairs with u for pk_fma
    ent.w = __builtin_bit_cast(unsigned, u);
    kvbuf[bb][tok] = ent;

    // q scaled by log2(e)/sqrt(4): folds softmax scale and exp->exp2
    const float QS = 0.7213475204f;
    h2 q01 = {(_Float16)(qv[0] * QS), (_Float16)(qv[1] * QS)};
    h2 q23 = {(_Float16)(qv[2] * QS), (_Float16)(qv[3] * QS)};

    __syncthreads();

    // ---- attention, lane-quad version: quad {t^0..t^3} covers rows
    //      {tok^0..tok^3}; lane qd reads j = 4*jj + qd (consecutive entries
    //      per wave -> distinct banks, free broadcast).  Slot m of this lane
    //      accumulates row tok^m over this lane's j-subset. ----
    unsigned q01u = __builtin_bit_cast(unsigned, q01);
    unsigned q23u = __builtin_bit_cast(unsigned, q23);
    unsigned q01m[4], q23m[4];
    q01m[0] = q01u;
    q23m[0] = q23u;
    q01m[1] = __shfl_xor(q01u, 1);  q23m[1] = __shfl_xor(q23u, 1);
    q01m[2] = __shfl_xor(q01u, 2);  q23m[2] = __shfl_xor(q23u, 2);
    q01m[3] = __shfl_xor(q01u, 3);  q23m[3] = __shfl_xor(q23u, 3);

    const uint4* __restrict__ base = kvbuf[bb];
    f2 acc[4] = {f2{0.f, 0.f}, f2{0.f, 0.f}, f2{0.f, 0.f}, f2{0.f, 0.f}};
    #pragma unroll 4
    for (int jj = 0; jj < 32; ++jj) {
        uint4 c = base[4 * jj + qd];   // 4 consecutive entries/wave, bank-clean
        h2 k01 = __builtin_bit_cast(h2, c.x);
        h2 k23 = __builtin_bit_cast(h2, c.y);
        f2 du;
        du.x = __builtin_bit_cast(float, c.z);   // 1.0f
        du.y = __builtin_bit_cast(float, c.w);   // u
        #pragma unroll
        for (int m = 0; m < 4; ++m) {
            h2 qa = __builtin_bit_cast(h2, q01m[m]);
            h2 qb = __builtin_bit_cast(h2, q23m[m]);
            float s = dot2acc(qa, k01, dot2acc(qb, k23, 0.f));
            f2 e; e.x = fexp2(s);              // hi word undef (ok)
            pk_fma_bcast(acc[m], e, du);       // {d,n} += e * {1,u}
        }
    }

    // butterfly combine; only slot 0 (own row) survives.
    // step 1 (xor 1): need slots 0 and 2 post-combine; partner reads acc[1],acc[3].
    f2 n0 = acc[0] + shfl_f2(acc[1], 1);
    f2 n2 = acc[2] + shfl_f2(acc[3], 1);
    // step 2 (xor 2): slot 0 final; partner reads my n2 via the same shfl.
    f2 r  = n0 + shfl_f2(n2, 2);

    float z = fmaf(r.y, fast_rcp(r.x), b_fc[0]);
    out[(size_t)batch * 128 + tok] = fast_sigmoid(z);
}

extern "C" void kernel_launch(void* const* d_in, const int* in_sizes, int n_in,
                              void* d_out, int out_size, void* d_ws, size_t ws_size,
                              hipStream_t stream) {
    const float* x    = (const float*)d_in[0];
    const float* w_fm = (const float*)d_in[1];
    const float* b_fm = (const float*)d_in[2];
    const float* w_c1 = (const float*)d_in[3];
    const float* b_c1 = (const float*)d_in[4];
    const float* w_p1 = (const float*)d_in[5];
    const float* b_p1 = (const float*)d_in[6];
    const float* w_c2 = (const float*)d_in[7];
    const float* b_c2 = (const float*)d_in[8];
    const float* w_p2 = (const float*)d_in[9];
    const float* b_p2 = (const float*)d_in[10];
    const float* w_c3 = (const float*)d_in[11];
    const float* b_c3 = (const float*)d_in[12];
    const float* w_q  = (const float*)d_in[13];
    const float* w_k  = (const float*)d_in[14];
    const float* w_v  = (const float*)d_in[15];
    const float* w_fc = (const float*)d_in[16];
    const float* b_fc = (const float*)d_in[17];
    float* out = (float*)d_out;

    dim3 grid(1024);   // 2 batches per workgroup (frontier config)
    dim3 block(256);
    qcnn_fused_kernel<<<grid, block, 0, stream>>>(
        x, w_fm, b_fm, w_c1, b_c1, w_p1, b_p1, w_c2, b_c2,
        w_p2, b_p2, w_c3, b_c3, w_q, w_k, w_v, w_fc, b_fc, out);
}

// Round 13
// 20.046 us; speedup vs baseline: 1.3455x; 1.0146x over previous
//
#include <hip/hip_runtime.h>

#define DEV __device__ __forceinline__

typedef _Float16 h2 __attribute__((ext_vector_type(2)));
typedef float    f2 __attribute__((ext_vector_type(2)));

DEV float fast_rcp(float x) { return __builtin_amdgcn_rcpf(x); }

DEV float fexp2(float x) {
#if __has_builtin(__builtin_amdgcn_exp2f)
    return __builtin_amdgcn_exp2f(x);
#else
    float r; asm("v_exp_f32 %0, %1" : "=v"(r) : "v"(x)); return r;
#endif
}

DEV float dot2acc(h2 a, h2 b, float c) {
#if __has_builtin(__builtin_amdgcn_fdot2)
    return __builtin_amdgcn_fdot2(a, b, c, false);
#else
    return c + (float)a.x * (float)b.x + (float)a.y * (float)b.y;
#endif
}

// acc = w2 * in2 + acc (packed f32). w2 uniform -> SGPR pair.
DEV void pk_fma(f2& acc, f2 w2, f2 in2) {
    asm("v_pk_fma_f32 %0, %1, %2, %0" : "+v"(acc) : "s"(w2), "v"(in2));
}
// acc = w2 * in2 + 0  (inline-0 C: no accumulator init movs).
DEV f2 pk_fma_z(f2 w2, f2 in2) {
    f2 d;
    asm("v_pk_fma_f32 %0, %1, %2, 0 op_sel_hi:[1,1,0]"
        : "=v"(d) : "s"(w2), "v"(in2));
    return d;
}
// acc += broadcast(e.x) * du   (du = {1.0, u} pair straight from LDS).
DEV void pk_fma_bcast(f2& acc, f2 e, f2 du) {
    asm("v_pk_fma_f32 %0, %1, %2, %0 op_sel:[0,0,0] op_sel_hi:[0,1,1]"
        : "+v"(acc) : "v"(e), "v"(du));
}

// tanh from pre-scaled input t = 2*log2(e)*(Wx+b): 1 - 2/(exp2(t)+1).
DEV float fast_tanh_pre(float t) {
    float e = fexp2(t);
    return 1.0f - 2.0f * fast_rcp(e + 1.0f);
}
DEV float fast_sigmoid(float x) {
    return fast_rcp(1.0f + fexp2(x * -1.442695041f));
}

#define TANH_K 2.885390082f   // 2*log2(e)

// MLP layer, input-pair packed weights via uniform s_load_dwordx2.
// Bias folded into the tanh-input FMA: t = dot*K + (b*K).
template <int IN, int OUT, bool TANH>
DEV void layer_pk(const float* __restrict__ w, const float* __restrict__ b,
                  float vK, const float (&in)[IN], float (&out)[OUT]) {
    static_assert(IN % 2 == 0, "IN must be even");
    f2 in2[IN / 2];
    #pragma unroll
    for (int ip = 0; ip < IN / 2; ++ip) in2[ip] = f2{in[2 * ip], in[2 * ip + 1]};
    #pragma unroll
    for (int o = 0; o < OUT; ++o) {
        f2 acc = pk_fma_z(*reinterpret_cast<const f2*>(w + o * IN), in2[0]);
        #pragma unroll
        for (int ip = 1; ip < IN / 2; ++ip)
            pk_fma(acc, *reinterpret_cast<const f2*>(w + o * IN + 2 * ip), in2[ip]);
        float s = acc.x + acc.y;
        if (TANH) {
            float bk = b[o] * vK;           // v_mul: sgpr bias x vgpr K
            out[o] = fast_tanh_pre(fmaf(s, vK, bk));
        } else {
            out[o] = s;
        }
    }
}

// block=256, min 4 waves/EU: hard-caps VGPR at 128 so 4 blocks/CU are
// co-resident (16 waves/CU) -> single occupancy round over the 1024-wg grid.
__global__ __launch_bounds__(256, 4)
void qcnn_fused_kernel(const float* __restrict__ x,
                       const float* __restrict__ w_fm, const float* __restrict__ b_fm,
                       const float* __restrict__ w_c1, const float* __restrict__ b_c1,
                       const float* __restrict__ w_p1, const float* __restrict__ b_p1,
                       const float* __restrict__ w_c2, const float* __restrict__ b_c2,
                       const float* __restrict__ w_p2, const float* __restrict__ b_p2,
                       const float* __restrict__ w_c3, const float* __restrict__ b_c3,
                       const float* __restrict__ w_q,  const float* __restrict__ w_k,
                       const float* __restrict__ w_v,
                       const float* __restrict__ w_fc, const float* __restrict__ b_fc,
                       float* __restrict__ out) {
    const int t     = threadIdx.x;          // 0..255
    const int bb    = t >> 7;               // sub-batch 0/1 within block
    const int tok   = t & 127;              // token 0..127
    const int batch = blockIdx.x * 2 + bb;  // 0..2047

    // per-token entry: x=k01(fp16x2) y=k23(fp16x2) z=1.0f w=u(f32)
    __shared__ uint4 kvbuf[2][128];

    const float vK = TANH_K;                // hoisted VGPR constant

    // ---- load x[batch][tok][0:8] (coalesced, 32 B/thread) ----
    const float* xp = x + ((size_t)batch * 128 + tok) * 8;
    float4 x0 = *reinterpret_cast<const float4*>(xp);
    float4 x1 = *reinterpret_cast<const float4*>(xp + 4);
    float xin[8] = {x0.x, x0.y, x0.z, x0.w, x1.x, x1.y, x1.z, x1.w};

    // ---- MLP tower, packed-pair f32 FMA; weights via uniform scalar loads ----
    float h1[16], h2a[16], h3[12], h4[8], h5[4], h6[4];
    layer_pk<8, 16, true>(w_fm, b_fm, vK, xin, h1);
    layer_pk<16, 16, true>(w_c1, b_c1, vK, h1, h2a);
    layer_pk<16, 12, true>(w_p1, b_p1, vK, h2a, h3);
    layer_pk<12, 8, true>(w_c2, b_c2, vK, h3, h4);
    layer_pk<8, 4, true>(w_p2, b_p2, vK, h4, h5);
    layer_pk<4, 4, true>(w_c3, b_c3, vK, h5, h6);

    float qv[4], kk[4];
    layer_pk<4, 4, false>(w_q, nullptr, vK, h6, qv);
    layer_pk<4, 4, false>(w_k, nullptr, vK, h6, kk);

    // ---- fc folded into V: u = (w_fc^T W_v) . h6 (uniform weights) ----
    float wf[4];
    #pragma unroll
    for (int i = 0; i < 4; ++i)
        wf[i] = fmaf(w_fc[0], w_v[0 * 4 + i],
                fmaf(w_fc[1], w_v[1 * 4 + i],
                fmaf(w_fc[2], w_v[2 * 4 + i], w_fc[3] * w_v[3 * 4 + i])));
    float u = fmaf(wf[0], h6[0], fmaf(wf[1], h6[1], fmaf(wf[2], h6[2], wf[3] * h6[3])));

    h2 pk01 = {(_Float16)kk[0], (_Float16)kk[1]};
    h2 pk23 = {(_Float16)kk[2], (_Float16)kk[3]};
    uint4 ent;
    ent.x = __builtin_bit_cast(unsigned, pk01);
    ent.y = __builtin_bit_cast(unsigned, pk23);
    ent.z = __builtin_bit_cast(unsigned, 1.0f);   // pairs with u for pk_fma
    ent.w = __builtin_bit_cast(unsigned, u);
    kvbuf[bb][tok] = ent;

    // q scaled by log2(e)/sqrt(4): folds softmax scale and exp->exp2
    const float QS = 0.7213475204f;
    h2 q01 = {(_Float16)(qv[0] * QS), (_Float16)(qv[1] * QS)};
    h2 q23 = {(_Float16)(qv[2] * QS), (_Float16)(qv[3] * QS)};

    __syncthreads();

    // ---- attention: adjacent-lane pair covers rows {tok&~1, tok|1};
    //      parity picks the j-half; combine via shfl_xor(1) ----
    unsigned q01u = __builtin_bit_cast(unsigned, q01);
    unsigned q23u = __builtin_bit_cast(unsigned, q23);
    unsigned q01o = __shfl_xor(q01u, 1);
    unsigned q23o = __shfl_xor(q23u, 1);
    const bool odd = (t & 1);
    h2 q01_r0 = __builtin_bit_cast(h2, odd ? q01o : q01u);
    h2 q23_r0 = __builtin_bit_cast(h2, odd ? q23o : q23u);
    h2 q01_r1 = __builtin_bit_cast(h2, odd ? q01u : q01o);
    h2 q23_r1 = __builtin_bit_cast(h2, odd ? q23u : q23o);

    const uint4* __restrict__ base = kvbuf[bb] + (odd ? 64 : 0);
    f2 acc0 = {0.f, 0.f};   // {denom, numerator} for row r0 (this lane's j-half)
    f2 acc1 = {0.f, 0.f};   // same for row r1
    #pragma unroll 8
    for (int j = 0; j < 64; ++j) {
        uint4 c = base[j];       // 2 addresses/wave -> free broadcast
        h2 k01 = __builtin_bit_cast(h2, c.x);
        h2 k23 = __builtin_bit_cast(h2, c.y);
        f2 du;                   // {1.0, u} directly from the b128 read
        du.x = __builtin_bit_cast(float, c.z);
        du.y = __builtin_bit_cast(float, c.w);
        float s0 = dot2acc(q01_r0, k01, dot2acc(q23_r0, k23, 0.f));
        float s1 = dot2acc(q01_r1, k01, dot2acc(q23_r1, k23, 0.f));
        f2 e0; e0.x = fexp2(s0);          // hi word intentionally undef
        f2 e1; e1.x = fexp2(s1);
        pk_fma_bcast(acc0, e0, du);       // {d,n} += e * {1, u}
        pk_fma_bcast(acc1, e1, du);
    }

    // combine lane-pair partials (each row's j-halves in adjacent lanes)
    f2 p0, p1;
    p0.x = __shfl_xor(acc0.x, 1);  p0.y = __shfl_xor(acc0.y, 1);
    p1.x = __shfl_xor(acc1.x, 1);  p1.y = __shfl_xor(acc1.y, 1);
    acc0 += p0;
    acc1 += p1;

    float dd = odd ? acc1.x : acc0.x;
    float uu = odd ? acc1.y : acc0.y;
    float z = fmaf(uu, fast_rcp(dd), b_fc[0]);
    out[(size_t)batch * 128 + tok] = fast_sigmoid(z);
}

extern "C" void kernel_launch(void* const* d_in, const int* in_sizes, int n_in,
                              void* d_out, int out_size, void* d_ws, size_t ws_size,
                              hipStream_t stream) {
    const float* x    = (const float*)d_in[0];
    const float* w_fm = (const float*)d_in[1];
    const float* b_fm = (const float*)d_in[2];
    const float* w_c1 = (const float*)d_in[3];
    const float* b_c1 = (const float*)d_in[4];
    const float* w_p1 = (const float*)d_in[5];
    const float* b_p1 = (const float*)d_in[6];
    const float* w_c2 = (const float*)d_in[7];
    const float* b_c2 = (const float*)d_in[8];
    const float* w_p2 = (const float*)d_in[9];
    const float* b_p2 = (const float*)d_in[10];
    const float* w_c3 = (const float*)d_in[11];
    const float* b_c3 = (const float*)d_in[12];
    const float* w_q  = (const float*)d_in[13];
    const float* w_k  = (const float*)d_in[14];
    const float* w_v  = (const float*)d_in[15];
    const float* w_fc = (const float*)d_in[16];
    const float* b_fc = (const float*)d_in[17];
    float* out = (float*)d_out;

    dim3 grid(1024);   // 2 batches per workgroup (frontier config)
    dim3 block(256);
    qcnn_fused_kernel<<<grid, block, 0, stream>>>(
        x, w_fm, b_fm, w_c1, b_c1, w_p1, b_p1, w_c2, b_c2,
        w_p2, b_p2, w_c3, b_c3, w_q, w_k, w_v, w_fc, b_fc, out);
}